// Round 11
// baseline (279.831 us; speedup 1.0000x reference)
//
#include <hip/hip_runtime.h>
#include <hip/hip_bf16.h>
#include <hip/hip_cooperative_groups.h>

namespace cg = cooperative_groups;

// Problem constants
#define NROW 8192
#define DDIM 512
#define TEMP_INV 20.0f      // 1/0.05
#define SHIFT 20.0f         // sim <= 20, accumulate exp(sim-20)

// GEMM geometry: 256x256 tile, BK=64, 8 waves (2M x 4N), 2-buffer LDS,
// 8-phase interleave per 2 K-tiles (round-8 structure, verified 0 conflicts,
// no spill). Round 9: ONE fused cooperative kernel, 256 persistent blocks
// (1/CU): normalize -> grid.sync -> each block sweeps 4 column-tiles with
// the wrap-staging retargeted to the next q's bcol (pipeline never drains
// across q) -> grid.sync -> log-reduce. Kills the ~66us multi-kernel
// residual + 3/4 of per-block prologue/epilogue/redispatch overhead.
#define BM 256
#define BN 256
#define BK 64
#define KT (DDIM / BK)            // 8 K-tiles per column-tile
#define TILE_A_ELE (BM * BK)      // 16384 bf16 (A region; B same)
#define BUF_ELE (2 * TILE_A_ELE)  // A+B per buffer
#define LDS_BYTES (2 * BUF_ELE * 2)  // 131072

typedef __attribute__((ext_vector_type(8))) short short8;
typedef __attribute__((ext_vector_type(4))) float f32x4;

__device__ __forceinline__ void gload16(const __hip_bfloat16* g, __hip_bfloat16* l) {
  __builtin_amdgcn_global_load_lds(
      (const __attribute__((address_space(1))) void*)g,
      (__attribute__((address_space(3))) void*)l,
      16, 0, 0);
}

#define VMC(N) asm volatile("s_waitcnt vmcnt(" #N ")" ::: "memory")
#define SBAR()                          \
  do {                                  \
    __builtin_amdgcn_s_barrier();       \
    __builtin_amdgcn_sched_barrier(0);  \
  } while (0)

// 16B swizzled-slot LDS fragment loads. LDS[row][slot'] holds global
// 16B-slot slot'^(row&7) (0 bank conflicts, verified rounds 1/4/5/6/8).
#define LDSA(BUFB, QM, MI, KK)                                                \
  (*reinterpret_cast<const short8*>(                                          \
      &lds[(size_t)(BUFB) * BUF_ELE +                                         \
           (wr * 128 + (QM) * 64 + (MI) * 16 + l15) * BK +                    \
           ((((KK) * 4 + hi) ^ x7) * 8)]))
#define LDSB(BUFB, QN, NI, KK)                                                \
  (*reinterpret_cast<const short8*>(                                          \
      &lds[(size_t)(BUFB) * BUF_ELE + TILE_A_ELE +                            \
           (wc * 64 + (QN) * 32 + (NI) * 16 + l15) * BK +                     \
           ((((KK) * 4 + hi) ^ x7) * 8)]))

// 4 MFMAs for one A row-block MI against a 4-frag B register set
#define MF4(QM, MI, QN, BF)                                                   \
  acc[(QM) * 4 + (MI)][(QN) * 2 + 0] =                                        \
      __builtin_amdgcn_mfma_f32_16x16x32_bf16(                                \
          af[(MI) * 2 + 0], (BF)[0], acc[(QM) * 4 + (MI)][(QN) * 2 + 0],      \
          0, 0, 0);                                                           \
  acc[(QM) * 4 + (MI)][(QN) * 2 + 0] =                                        \
      __builtin_amdgcn_mfma_f32_16x16x32_bf16(                                \
          af[(MI) * 2 + 1], (BF)[1], acc[(QM) * 4 + (MI)][(QN) * 2 + 0],      \
          0, 0, 0);                                                           \
  acc[(QM) * 4 + (MI)][(QN) * 2 + 1] =                                        \
      __builtin_amdgcn_mfma_f32_16x16x32_bf16(                                \
          af[(MI) * 2 + 0], (BF)[2], acc[(QM) * 4 + (MI)][(QN) * 2 + 1],      \
          0, 0, 0);                                                           \
  acc[(QM) * 4 + (MI)][(QN) * 2 + 1] =                                        \
      __builtin_amdgcn_mfma_f32_16x16x32_bf16(                                \
          af[(MI) * 2 + 1], (BF)[3], acc[(QM) * 4 + (MI)][(QN) * 2 + 1],      \
          0, 0, 0);

// A-phase: read 8 af frags, stage one half-tile, barrier, q(QM,0) w/ bf0.
#define PHASE_A(BUFB, QM, ST, H)                                              \
  do {                                                                        \
    af[0] = LDSA(BUFB, QM, 0, 0); af[1] = LDSA(BUFB, QM, 0, 1);               \
    af[2] = LDSA(BUFB, QM, 1, 0); af[3] = LDSA(BUFB, QM, 1, 1);               \
    STAGE_HALF(ST, H);                                                        \
    af[4] = LDSA(BUFB, QM, 2, 0); af[5] = LDSA(BUFB, QM, 2, 1);               \
    af[6] = LDSA(BUFB, QM, 3, 0); af[7] = LDSA(BUFB, QM, 3, 1);               \
    SBAR();                                                                   \
    __builtin_amdgcn_s_setprio(1);                                            \
    MF4(QM, 0, 0, bf0) MF4(QM, 1, 0, bf0)                                     \
    MF4(QM, 2, 0, bf0) MF4(QM, 3, 0, bf0)                                     \
    __builtin_amdgcn_s_setprio(0);                                            \
    SBAR();                                                                   \
  } while (0)

// B-phase: read bf1 (qn=1), stage, barrier, q(0,1) w/ live af (=af0).
#define PHASE_B(BUFB, ST, H)                                                  \
  do {                                                                        \
    bf1[0] = LDSB(BUFB, 1, 0, 0); bf1[1] = LDSB(BUFB, 1, 0, 1);               \
    bf1[2] = LDSB(BUFB, 1, 1, 0); bf1[3] = LDSB(BUFB, 1, 1, 1);               \
    STAGE_HALF(ST, H);                                                        \
    SBAR();                                                                   \
    __builtin_amdgcn_s_setprio(1);                                            \
    MF4(0, 0, 1, bf1) MF4(0, 1, 1, bf1)                                       \
    MF4(0, 2, 1, bf1) MF4(0, 3, 1, bf1)                                       \
    __builtin_amdgcn_s_setprio(0);                                            \
    SBAR();                                                                   \
  } while (0)

// Wait-phase: stage next tile's h0, counted vmcnt proves the prefetch tile
// landed, barrier publishes it, pre-read its bf0 while computing q(1,1).
#define PHASE_W(ST, PBUF)                                                     \
  do {                                                                        \
    STAGE_HALF(ST, 0);                                                        \
    VMC(2);                                                                   \
    SBAR();                                                                   \
    bf0[0] = LDSB(PBUF, 0, 0, 0); bf0[1] = LDSB(PBUF, 0, 0, 1);               \
    bf0[2] = LDSB(PBUF, 0, 1, 0); bf0[3] = LDSB(PBUF, 0, 1, 1);               \
    __builtin_amdgcn_s_setprio(1);                                            \
    MF4(1, 0, 1, bf1) MF4(1, 1, 1, bf1)                                       \
    MF4(1, 2, 1, bf1) MF4(1, 3, 1, bf1)                                       \
    __builtin_amdgcn_s_setprio(0);                                            \
    SBAR();                                                                   \
  } while (0)

// -------------------------------------------------------------------------
// Fused cooperative kernel: normalize -> sync -> persistent GEMM+LSE ->
// sync -> partial log-reduce -> sync -> final reduce.
// -------------------------------------------------------------------------
__global__ __launch_bounds__(512, 2) void fused_contrastive(
    const float* __restrict__ z1, const float* __restrict__ z2,
    __hip_bfloat16* __restrict__ z1n, __hip_bfloat16* __restrict__ z2n,
    float* __restrict__ rowsum, float* __restrict__ partial,
    float* __restrict__ out) {
  extern __shared__ __align__(16) __hip_bfloat16 lds[];
  cg::grid_group grid = cg::this_grid();

  const int tid = threadIdx.x;
  const int lane = tid & 63;

  // ---- stage 1: row-normalize to bf16 (z1 scaled by 1/temp), zero rowsum --
  {
    const int wv = (blockIdx.x << 3) + (tid >> 6);   // 0..2047
    for (int j = 0; j < 8; ++j) {
      const int row = wv * 8 + j;                    // 0..16383
      const float* src;
      __hip_bfloat16* dst;
      float numer;
      if (row < NROW) {
        src = z1 + (size_t)row * DDIM;
        dst = z1n + (size_t)row * DDIM;
        numer = TEMP_INV;
        if (lane == 0) rowsum[row] = 0.0f;
      } else {
        const int r = row - NROW;
        src = z2 + (size_t)r * DDIM;
        dst = z2n + (size_t)r * DDIM;
        numer = 1.0f;
      }
      float4 v0 = *reinterpret_cast<const float4*>(src + lane * 8);
      float4 v1 = *reinterpret_cast<const float4*>(src + lane * 8 + 4);
      float ss = v0.x * v0.x + v0.y * v0.y + v0.z * v0.z + v0.w * v0.w +
                 v1.x * v1.x + v1.y * v1.y + v1.z * v1.z + v1.w * v1.w;
#pragma unroll
      for (int off = 32; off; off >>= 1) ss += __shfl_xor(ss, off);
      float scale = numer / fmaxf(sqrtf(ss), 1e-8f);
      float vals[8] = {v0.x, v0.y, v0.z, v0.w, v1.x, v1.y, v1.z, v1.w};
      union { __hip_bfloat16 h[8]; uint4 q; } pk;
#pragma unroll
      for (int k = 0; k < 8; ++k) pk.h[k] = __float2bfloat16(vals[k] * scale);
      *reinterpret_cast<uint4*>(dst + lane * 8) = pk.q;
    }
  }
  grid.sync();

  // ---- stage 2: persistent GEMM + exp epilogue + rowsum atomics ----
  {
    // XCD map: xcd = bid&7; each XCD owns 4 A-panels (1MB, L2-hot); per q
    // its 32 blocks touch 8 B-panels (2MB). Block sweeps bx = bxq*4+q.
    const int xcd = blockIdx.x & 7;
    const int idx = blockIdx.x >> 3;     // 0..31
    const int by = xcd * 4 + (idx & 3);
    const int bxq = idx >> 2;            // 0..7
    const int brow = by * BM;

    const int w = tid >> 6;              // wave 0..7
    const int wr = w >> 2;               // 0..1: rows [wr*128, +128)
    const int wc = w & 3;                // 0..3: cols [wc*64, +64)

    f32x4 acc[8][4];
#pragma unroll
    for (int m = 0; m < 8; ++m)
#pragma unroll
      for (int n = 0; n < 4; ++n) acc[m][n] = (f32x4)0.0f;

    const int srow8 = lane >> 3;               // 0..7
    const int sslot = (lane & 7) ^ srow8;      // pre-swizzled source slot

    int bcol = (bxq * 4) * BN;       // q=0 columns
    int bcol_next = bcol + BN;       // wrap-stage (st>=KT) target

    auto STAGE_HALF = [&](int st, int h) {
      const int stm = st & (KT - 1);           // st>=KT: next-q tile 0/1
      const int bc = (st >= KT) ? bcol_next : bcol;
      const __hip_bfloat16* gbase =
          (h < 2) ? z1n + (size_t)brow * DDIM : z2n + (size_t)bc * DDIM;
      const int rowt = (h & 1) * 128 + w * 16;
      const __hip_bfloat16* g =
          gbase + (size_t)(rowt + srow8) * DDIM + stm * BK + sslot * 8;
      __hip_bfloat16* dst = lds + (size_t)(stm & 1) * BUF_ELE +
                            ((h >= 2) ? TILE_A_ELE : 0) + rowt * BK;
      gload16(g, dst);
      gload16(g + (size_t)8 * DDIM, dst + 8 * BK);
    };

    const int hi = lane >> 4;
    const int l15 = lane & 15;
    const int x7 = lane & 7;

    short8 af[8], bf0[4], bf1[4];

    // prologue (q=0 only; q>0 inherits pipeline via wrap-stages)
    STAGE_HALF(0, 0); STAGE_HALF(0, 1); STAGE_HALF(0, 2); STAGE_HALF(0, 3);
    STAGE_HALF(1, 0);
    VMC(2);
    SBAR();
    bf0[0] = LDSB(0, 0, 0, 0); bf0[1] = LDSB(0, 0, 0, 1);
    bf0[2] = LDSB(0, 0, 1, 0); bf0[3] = LDSB(0, 0, 1, 1);

    const float L2E = 1.4426950408889634f;
    const float NEG = -SHIFT * 1.4426950408889634f;

    for (int q = 0; q < 4; ++q) {
      bcol = (bxq * 4 + q) * BN;
      bcol_next = (bxq * 4 + ((q + 1) & 3)) * BN;  // q=3 wrap: staged, never read

      for (int i = 0; i < KT / 2; ++i) {
        const int t1 = 2 * i + 1, t2 = 2 * i + 2, t3 = 2 * i + 3;
        PHASE_A(0, 0, t1, 1);   // ph1: read af0(buf0), q(0,0) w/ pre-read bf0
        PHASE_B(0, t1, 2);      // ph2: read bf1(buf0), q(0,1)
        PHASE_A(0, 1, t1, 3);   // ph3: read af1(buf0), q(1,0)
        PHASE_W(t2, 1);         // ph4: q(1,1); pre-read bf0 <- buf1
        PHASE_A(1, 0, t2, 1);   // ph5
        PHASE_B(1, t2, 2);      // ph6
        PHASE_A(1, 1, t2, 3);   // ph7
        PHASE_W(t3, 0);         // ph8: q(1,1); pre-read bf0 <- buf0 (next pair)
      }
      // epilogue(q): exp(sim-20), 16-lane col reduce, atomic accumulate.
      // C/D layout: col = lane&15, row = (lane>>4)*4 + reg  [m89/m91]
#pragma unroll
      for (int m = 0; m < 8; ++m) {
#pragma unroll
        for (int r = 0; r < 4; ++r) {
          float s = 0.0f;
#pragma unroll
          for (int n = 0; n < 4; ++n)
            s += exp2f(fmaf(acc[m][n][r], L2E, NEG));
          s += __shfl_xor(s, 1);
          s += __shfl_xor(s, 2);
          s += __shfl_xor(s, 4);
          s += __shfl_xor(s, 8);
          if (l15 == 0)
            atomicAdd(&rowsum[brow + wr * 128 + m * 16 + hi * 4 + r], s);
        }
      }
      // re-zero accumulator for next column-tile
#pragma unroll
      for (int m = 0; m < 8; ++m)
#pragma unroll
        for (int n = 0; n < 4; ++n) acc[m][n] = (f32x4)0.0f;
    }
    VMC(0);   // retire dead wrap-prefetches before leaving stage 2
  }
  grid.sync();

  // ---- stage 3: per-block partial log-sum (32 rows each) ----
  if (tid < 64) {
    float v = (tid < 32) ? logf(rowsum[blockIdx.x * 32 + tid]) : 0.0f;
#pragma unroll
    for (int off = 32; off; off >>= 1) v += __shfl_xor(v, off);
    if (tid == 0) partial[blockIdx.x] = v;
  }
  grid.sync();

  // ---- stage 4: final reduce ----
  if (blockIdx.x == 0 && tid < 64) {
    float v = 0.0f;
    for (int i = tid; i < 256; i += 64) v += partial[i];
#pragma unroll
    for (int off = 32; off; off >>= 1) v += __shfl_xor(v, off);
    if (tid == 0) out[0] = -(v / (float)NROW + SHIFT);
  }
}

// -------------------------------------------------------------------------
extern "C" void kernel_launch(void* const* d_in, const int* in_sizes, int n_in,
                              void* d_out, int out_size, void* d_ws,
                              size_t ws_size, hipStream_t stream) {
  const float* z1 = (const float*)d_in[0];
  const float* z2 = (const float*)d_in[1];
  float* out = (float*)d_out;

  char* ws = (char*)d_ws;
  __hip_bfloat16* z1n = (__hip_bfloat16*)ws;                               // 8 MB
  __hip_bfloat16* z2n = (__hip_bfloat16*)(ws + (size_t)NROW * DDIM * 2);   // 8 MB
  float* rowsum = (float*)(ws + (size_t)2 * NROW * DDIM * 2);              // 32 KB
  float* partial = (float*)(ws + (size_t)2 * NROW * DDIM * 2 + NROW * 4);  // 1 KB

  static bool attr_set = false;
  if (!attr_set) {
    hipFuncSetAttribute((const void*)fused_contrastive,
                        hipFuncAttributeMaxDynamicSharedMemorySize, LDS_BYTES);
    attr_set = true;
  }

  void* args[] = {(void*)&z1, (void*)&z2, (void*)&z1n, (void*)&z2n,
                  (void*)&rowsum, (void*)&partial, (void*)&out};
  hipLaunchCooperativeKernel((const void*)fused_contrastive, dim3(256),
                             dim3(512), args, LDS_BYTES, stream);
}

// Round 12
// 157.457 us; speedup vs baseline: 1.7772x; 1.7772x over previous
//
#include <hip/hip_runtime.h>
#include <hip/hip_fp8.h>

// Problem constants
#define NROW 8192
#define DDIM 512
#define SCALE 20.0f         // fold 1/temp as sqrt into BOTH sides: z*20 each,
                            // acc = 400*cos, sim = acc/20
#define SHIFT 20.0f         // sim <= 20, accumulate exp(sim-20)

// GEMM geometry: 256x256 tile, BK=64 (fp8: 64B rows), 8 waves (2M x 4N),
// 2-buffer LDS (64KB total), 8-phase interleave per 2 K-tiles, XCD
// supertile swizzle. Round 12: fp8 e4m3 operands at bf16 MFMA rate --
// halves ds_read/LDS/staging bytes (round-8 analysis: pipes serialized,
// LDS serve ~= MFMA time; halving LDS-side shrinks the serial sum).
#define BM 256
#define BN 256
#define BK 64
#define KT (DDIM / BK)            // 8 K-tiles
#define TILE_BYTES (BM * BK)      // 16384 B (one matrix region)
#define BUF_BYTES (2 * TILE_BYTES)
#define LDS_BYTES (2 * BUF_BYTES) // 65536

typedef __attribute__((ext_vector_type(4))) float f32x4;

__device__ __forceinline__ void gload16(const void* g, void* l) {
  __builtin_amdgcn_global_load_lds(
      (const __attribute__((address_space(1))) void*)g,
      (__attribute__((address_space(3))) void*)l,
      16, 0, 0);
}

__device__ __forceinline__ unsigned char to_e4m3(float x) {
  union { __hip_fp8_e4m3 f; unsigned char b; } u;
  u.f = __hip_fp8_e4m3(x);
  return u.b;
}

// -------------------------------------------------------------------------
// Kernel 1: row-normalize both inputs to fp8 e4m3, scaled by 20 (sqrt of
// 1/temperature folded into each side). Zero rowsum. One wave per row.
// -------------------------------------------------------------------------
__global__ __launch_bounds__(256) void normalize_rows(
    const float* __restrict__ z1, const float* __restrict__ z2,
    unsigned char* __restrict__ z1n, unsigned char* __restrict__ z2n,
    float* __restrict__ rowsum) {
  int row = blockIdx.x * 4 + (threadIdx.x >> 6);   // 0..16383
  int lane = threadIdx.x & 63;

  const float* src;
  unsigned char* dst;
  if (row < NROW) {
    src = z1 + (size_t)row * DDIM;
    dst = z1n + (size_t)row * DDIM;
    if (lane == 0) rowsum[row] = 0.0f;
  } else {
    int r = row - NROW;
    src = z2 + (size_t)r * DDIM;
    dst = z2n + (size_t)r * DDIM;
  }

  float4 v0 = *reinterpret_cast<const float4*>(src + lane * 8);
  float4 v1 = *reinterpret_cast<const float4*>(src + lane * 8 + 4);
  float ss = v0.x * v0.x + v0.y * v0.y + v0.z * v0.z + v0.w * v0.w +
             v1.x * v1.x + v1.y * v1.y + v1.z * v1.z + v1.w * v1.w;
#pragma unroll
  for (int off = 32; off; off >>= 1) ss += __shfl_xor(ss, off);

  float scale = SCALE / fmaxf(sqrtf(ss), 1e-8f);

  float vals[8] = {v0.x, v0.y, v0.z, v0.w, v1.x, v1.y, v1.z, v1.w};
  union { unsigned char b[8]; unsigned long long q; } pk;
#pragma unroll
  for (int j = 0; j < 8; ++j) pk.b[j] = to_e4m3(vals[j] * scale);
  *reinterpret_cast<unsigned long long*>(dst + lane * 8) = pk.q;
}

// -------------------------------------------------------------------------
// Kernel 2: fused fp8 GEMM (dots) + exp epilogue + per-row sum-of-exp.
// LDS swizzle (64B rows, 8B slots): LDS[row][s] holds global slot
// s ^ e8(row), e8 = ((row>>1)&3)<<1 -- even XOR keeps 16B gload pairs
// aligned; b64 frag reads are uniform 4-way (= minimum, conflict-free).
// -------------------------------------------------------------------------
#define VMC(N) asm volatile("s_waitcnt vmcnt(" #N ")" ::: "memory")
#define SBAR()                          \
  do {                                  \
    __builtin_amdgcn_s_barrier();       \
    __builtin_amdgcn_sched_barrier(0);  \
  } while (0)

#define LDSA(BUFB, QM, MI, KK)                                                \
  (*reinterpret_cast<const long long*>(                                       \
      &ldsc[(size_t)(BUFB) * BUF_BYTES +                                      \
            (wr * 128 + (QM) * 64 + (MI) * 16 + l15) * 64 +                   \
            ((((KK) * 4 + hi) ^ e8) * 8)]))
#define LDSB(BUFB, QN, NI, KK)                                                \
  (*reinterpret_cast<const long long*>(                                       \
      &ldsc[(size_t)(BUFB) * BUF_BYTES + TILE_BYTES +                         \
            (wc * 64 + (QN) * 32 + (NI) * 16 + l15) * 64 +                    \
            ((((KK) * 4 + hi) ^ e8) * 8)]))

#define MF4(QM, MI, QN, BF)                                                   \
  acc[(QM) * 4 + (MI)][(QN) * 2 + 0] =                                        \
      __builtin_amdgcn_mfma_f32_16x16x32_fp8_fp8(                             \
          af[(MI) * 2 + 0], (BF)[0], acc[(QM) * 4 + (MI)][(QN) * 2 + 0],      \
          0, 0, 0);                                                           \
  acc[(QM) * 4 + (MI)][(QN) * 2 + 0] =                                        \
      __builtin_amdgcn_mfma_f32_16x16x32_fp8_fp8(                             \
          af[(MI) * 2 + 1], (BF)[1], acc[(QM) * 4 + (MI)][(QN) * 2 + 0],      \
          0, 0, 0);                                                           \
  acc[(QM) * 4 + (MI)][(QN) * 2 + 1] =                                        \
      __builtin_amdgcn_mfma_f32_16x16x32_fp8_fp8(                             \
          af[(MI) * 2 + 0], (BF)[2], acc[(QM) * 4 + (MI)][(QN) * 2 + 1],      \
          0, 0, 0);                                                           \
  acc[(QM) * 4 + (MI)][(QN) * 2 + 1] =                                        \
      __builtin_amdgcn_mfma_f32_16x16x32_fp8_fp8(                             \
          af[(MI) * 2 + 1], (BF)[3], acc[(QM) * 4 + (MI)][(QN) * 2 + 1],      \
          0, 0, 0);

#define PHASE_A(BUFB, QM, ST, H)                                              \
  do {                                                                        \
    af[0] = LDSA(BUFB, QM, 0, 0); af[1] = LDSA(BUFB, QM, 0, 1);               \
    af[2] = LDSA(BUFB, QM, 1, 0); af[3] = LDSA(BUFB, QM, 1, 1);               \
    STAGE_HALF(ST, H);                                                        \
    af[4] = LDSA(BUFB, QM, 2, 0); af[5] = LDSA(BUFB, QM, 2, 1);               \
    af[6] = LDSA(BUFB, QM, 3, 0); af[7] = LDSA(BUFB, QM, 3, 1);               \
    SBAR();                                                                   \
    __builtin_amdgcn_s_setprio(1);                                            \
    MF4(QM, 0, 0, bf0) MF4(QM, 1, 0, bf0)                                     \
    MF4(QM, 2, 0, bf0) MF4(QM, 3, 0, bf0)                                     \
    __builtin_amdgcn_s_setprio(0);                                            \
    SBAR();                                                                   \
  } while (0)

#define PHASE_B(BUFB, ST, H)                                                  \
  do {                                                                        \
    bf1[0] = LDSB(BUFB, 1, 0, 0); bf1[1] = LDSB(BUFB, 1, 0, 1);               \
    bf1[2] = LDSB(BUFB, 1, 1, 0); bf1[3] = LDSB(BUFB, 1, 1, 1);               \
    STAGE_HALF(ST, H);                                                        \
    SBAR();                                                                   \
    __builtin_amdgcn_s_setprio(1);                                            \
    MF4(0, 0, 1, bf1) MF4(0, 1, 1, bf1)                                       \
    MF4(0, 2, 1, bf1) MF4(0, 3, 1, bf1)                                       \
    __builtin_amdgcn_s_setprio(0);                                            \
    SBAR();                                                                   \
  } while (0)

#define PHASE_W(ST, PBUF)                                                     \
  do {                                                                        \
    STAGE_HALF(ST, 0);                                                        \
    VMC(1);                                                                   \
    SBAR();                                                                   \
    bf0[0] = LDSB(PBUF, 0, 0, 0); bf0[1] = LDSB(PBUF, 0, 0, 1);               \
    bf0[2] = LDSB(PBUF, 0, 1, 0); bf0[3] = LDSB(PBUF, 0, 1, 1);               \
    __builtin_amdgcn_s_setprio(1);                                            \
    MF4(1, 0, 1, bf1) MF4(1, 1, 1, bf1)                                       \
    MF4(1, 2, 1, bf1) MF4(1, 3, 1, bf1)                                       \
    __builtin_amdgcn_s_setprio(0);                                            \
    SBAR();                                                                   \
  } while (0)

__global__ __launch_bounds__(512, 2) void gemm_lse(
    const unsigned char* __restrict__ An,   // z1n [N][D] fp8
    const unsigned char* __restrict__ Bn,   // z2n [N][D] fp8
    float* __restrict__ rowsum) {
  extern __shared__ __align__(16) char ldsc[];

  // ---- XCD-aware supertile swizzle (bijective over the 32x32 grid) ----
  const int bid = blockIdx.x;
  const int chunk = bid & 7;          // XCD id (round-robin dispatch)
  const int slot = bid >> 3;          // 0..127: per-XCD issue order
  const int by = chunk * 4 + ((slot >> 2) & 3);
  const int bx = (slot >> 4) * 4 + (slot & 3);
  const int brow = by * BM;
  const int bcol = bx * BN;

  const int tid = threadIdx.x;
  const int w = tid >> 6;             // wave 0..7
  const int lane = tid & 63;
  const int wr = w >> 2;              // 0..1: rows [wr*128, +128)
  const int wc = w & 3;               // 0..3: cols [wc*64, +64)

  f32x4 acc[8][4];
#pragma unroll
  for (int m = 0; m < 8; ++m)
#pragma unroll
    for (int n = 0; n < 4; ++n) acc[m][n] = (f32x4)0.0f;

  // ---- staging: 1 gload16 per half per wave (16 rows x 64B = 1KB) ----
  // lane l -> row l>>2, 16B-pair j = l&3; source pair = j ^ ((l>>3)&3)
  // (= pair-level inverse of the e8 read swizzle; rowt multiple of 16).
  const int srow = lane >> 2;                       // 0..15
  const int spair = (lane & 3) ^ ((lane >> 3) & 3); // swizzled source pair

  auto STAGE_HALF = [&](int st, int h) {
    const int stm = st & (KT - 1);           // wrap: dead prefetch on last iter
    const unsigned char* gbase =
        (h < 2) ? An + (size_t)brow * DDIM : Bn + (size_t)bcol * DDIM;
    const int rowt = (h & 1) * 128 + w * 16; // row within 256-row tile
    const unsigned char* g =
        gbase + (size_t)(rowt + srow) * DDIM + stm * BK + spair * 16;
    char* dst = ldsc + (size_t)(stm & 1) * BUF_BYTES +
                ((h >= 2) ? TILE_BYTES : 0) + rowt * 64;
    gload16(g, dst);
  };

  const int hi = lane >> 4;                 // 0..3 (k-group)
  const int l15 = lane & 15;
  const int e8 = ((l15 >> 1) & 3) << 1;     // even XOR on 8B-slot index

  // ---- prologue: tile0 fully + tile1 h0; VMC(1) -> tile0 landed ----
  STAGE_HALF(0, 0); STAGE_HALF(0, 1); STAGE_HALF(0, 2); STAGE_HALF(0, 3);
  STAGE_HALF(1, 0);
  VMC(1);
  SBAR();

  long long af[8], bf0[4], bf1[4];
  bf0[0] = LDSB(0, 0, 0, 0); bf0[1] = LDSB(0, 0, 0, 1);
  bf0[2] = LDSB(0, 0, 1, 0); bf0[3] = LDSB(0, 0, 1, 1);

  for (int i = 0; i < KT / 2; ++i) {
    // Tiles: T0 = 2i (buf0, ph1-4), T1 = 2i+1 (buf1, ph5-8).
    const int t1 = 2 * i + 1, t2 = 2 * i + 2, t3 = 2 * i + 3;
    PHASE_A(0, 0, t1, 1);   // ph1: read af0(buf0), q(0,0) w/ pre-read bf0
    PHASE_B(0, t1, 2);      // ph2: read bf1(buf0), q(0,1)
    PHASE_A(0, 1, t1, 3);   // ph3: read af1(buf0), q(1,0)
    PHASE_W(t2, 1);         // ph4: q(1,1); VMC(1) -> T1 landed; pre-read bf0
    PHASE_A(1, 0, t2, 1);   // ph5
    PHASE_B(1, t2, 2);      // ph6
    PHASE_A(1, 1, t2, 3);   // ph7
    PHASE_W(t3, 0);         // ph8: q(1,1); VMC(1) -> T2 landed; pre-read bf0
  }

  // ---- epilogue: acc = 400*cos; exp2(acc*L2E/20 - 20*L2E); col reduce ----
  // C/D layout: col = lane&15, row = (lane>>4)*4 + reg  [m89/m91]
  const float L2E20 = 1.4426950408889634f / 20.0f;
  const float NEG = -SHIFT * 1.4426950408889634f;
#pragma unroll
  for (int m = 0; m < 8; ++m) {
#pragma unroll
    for (int r = 0; r < 4; ++r) {
      float s = 0.0f;
#pragma unroll
      for (int n = 0; n < 4; ++n)
        s += exp2f(fmaf(acc[m][n][r], L2E20, NEG));
      s += __shfl_xor(s, 1);
      s += __shfl_xor(s, 2);
      s += __shfl_xor(s, 4);
      s += __shfl_xor(s, 8);
      if (l15 == 0)
        atomicAdd(&rowsum[brow + wr * 128 + m * 16 + hi * 4 + r], s);
    }
  }
}

// -------------------------------------------------------------------------
// Kernel 3: out = -( mean_i( log(rowsum_i) + 20 ) )
// -------------------------------------------------------------------------
__global__ __launch_bounds__(1024) void finalize_lse(
    const float* __restrict__ rowsum, float* __restrict__ out) {
  __shared__ float sm[16];
  float s = 0.0f;
  for (int i = threadIdx.x; i < NROW; i += 1024) s += logf(rowsum[i]);
#pragma unroll
  for (int off = 32; off; off >>= 1) s += __shfl_xor(s, off);
  int w = threadIdx.x >> 6;
  if ((threadIdx.x & 63) == 0) sm[w] = s;
  __syncthreads();
  if (threadIdx.x == 0) {
    float t = 0.0f;
#pragma unroll
    for (int i = 0; i < 16; ++i) t += sm[i];
    out[0] = -(t / (float)NROW + SHIFT);
  }
}

// -------------------------------------------------------------------------
extern "C" void kernel_launch(void* const* d_in, const int* in_sizes, int n_in,
                              void* d_out, int out_size, void* d_ws,
                              size_t ws_size, hipStream_t stream) {
  const float* z1 = (const float*)d_in[0];
  const float* z2 = (const float*)d_in[1];
  float* out = (float*)d_out;

  char* ws = (char*)d_ws;
  unsigned char* z1n = (unsigned char*)ws;                              // 4 MB
  unsigned char* z2n = (unsigned char*)(ws + (size_t)NROW * DDIM);      // 4 MB
  float* rowsum = (float*)(ws + (size_t)2 * NROW * DDIM);               // 32 KB

  static bool attr_set = false;
  if (!attr_set) {
    hipFuncSetAttribute((const void*)gemm_lse,
                        hipFuncAttributeMaxDynamicSharedMemorySize, LDS_BYTES);
    attr_set = true;
  }

  normalize_rows<<<dim3((2 * NROW) / 4), dim3(256), 0, stream>>>(z1, z2, z1n,
                                                                 z2n, rowsum);
  gemm_lse<<<dim3((NROW / BM) * (NROW / BN)), dim3(512), LDS_BYTES, stream>>>(
      z1n, z2n, rowsum);
  finalize_lse<<<dim3(1), dim3(1024), 0, stream>>>(rowsum, out);
}

// Round 13
// 153.384 us; speedup vs baseline: 1.8244x; 1.0266x over previous
//
#include <hip/hip_runtime.h>
#include <hip/hip_fp8.h>

// Problem constants
#define NROW 8192
#define DDIM 512
#define SCALE 20.0f         // fold 1/temp as sqrt into BOTH sides
#define SHIFT 20.0f         // sim <= 20, accumulate exp(sim-20)

// Round 13: ONE phase per K-tile (fp8 frags fit: 48 VGPR/tile), single
// barrier per phase, 4-deep LDS ring (4 x 32KB). Barrier-pairs per block
// drop 32 -> 8; per-phase MFMA content 512 -> 2048 cyc/SIMD so the ~1.1k
// fixed phase overhead (round-12 accounting) amortizes 4x.
#define BM 256
#define BN 256
#define BK 64                     // bytes per row (fp8)
#define KT (DDIM / BK)            // 8 K-tiles
#define TILE_BYTES (BM * BK)      // 16384 B per matrix region
#define BUF_BYTES (2 * TILE_BYTES)// 32768 B (A+B)
#define LDS_BYTES (4 * BUF_BYTES) // 131072

typedef __attribute__((ext_vector_type(4))) float f32x4;

__device__ __forceinline__ void gload16(const void* g, void* l) {
  __builtin_amdgcn_global_load_lds(
      (const __attribute__((address_space(1))) void*)g,
      (__attribute__((address_space(3))) void*)l,
      16, 0, 0);
}

__device__ __forceinline__ unsigned char to_e4m3(float x) {
  union { __hip_fp8_e4m3 f; unsigned char b; } u;
  u.f = __hip_fp8_e4m3(x);
  return u.b;
}

// -------------------------------------------------------------------------
// Kernel 1: row-normalize both inputs to fp8 e4m3, scaled by 20. Zero
// rowsum. One wave per row. (Unchanged from round 12 — verified.)
// -------------------------------------------------------------------------
__global__ __launch_bounds__(256) void normalize_rows(
    const float* __restrict__ z1, const float* __restrict__ z2,
    unsigned char* __restrict__ z1n, unsigned char* __restrict__ z2n,
    float* __restrict__ rowsum) {
  int row = blockIdx.x * 4 + (threadIdx.x >> 6);   // 0..16383
  int lane = threadIdx.x & 63;

  const float* src;
  unsigned char* dst;
  if (row < NROW) {
    src = z1 + (size_t)row * DDIM;
    dst = z1n + (size_t)row * DDIM;
    if (lane == 0) rowsum[row] = 0.0f;
  } else {
    int r = row - NROW;
    src = z2 + (size_t)r * DDIM;
    dst = z2n + (size_t)r * DDIM;
  }

  float4 v0 = *reinterpret_cast<const float4*>(src + lane * 8);
  float4 v1 = *reinterpret_cast<const float4*>(src + lane * 8 + 4);
  float ss = v0.x * v0.x + v0.y * v0.y + v0.z * v0.z + v0.w * v0.w +
             v1.x * v1.x + v1.y * v1.y + v1.z * v1.z + v1.w * v1.w;
#pragma unroll
  for (int off = 32; off; off >>= 1) ss += __shfl_xor(ss, off);

  float scale = SCALE / fmaxf(sqrtf(ss), 1e-8f);

  float vals[8] = {v0.x, v0.y, v0.z, v0.w, v1.x, v1.y, v1.z, v1.w};
  union { unsigned char b[8]; unsigned long long q; } pk;
#pragma unroll
  for (int j = 0; j < 8; ++j) pk.b[j] = to_e4m3(vals[j] * scale);
  *reinterpret_cast<unsigned long long*>(dst + lane * 8) = pk.q;
}

// -------------------------------------------------------------------------
// Kernel 2: fused fp8 GEMM + exp epilogue + per-row sum-of-exp.
// LDS layout/swizzle identical to round 12 (correctness-verified):
// LDS[row][s8] holds global 8B-slot s8 ^ e8(row), e8 = ((row>>1)&3)<<1.
// -------------------------------------------------------------------------
#define VMC(N) asm volatile("s_waitcnt vmcnt(" #N ")" ::: "memory")
#define SBAR()                          \
  do {                                  \
    __builtin_amdgcn_s_barrier();       \
    __builtin_amdgcn_sched_barrier(0);  \
  } while (0)

__global__ __launch_bounds__(512, 2) void gemm_lse(
    const unsigned char* __restrict__ An,   // z1n [N][D] fp8
    const unsigned char* __restrict__ Bn,   // z2n [N][D] fp8
    float* __restrict__ rowsum) {
  extern __shared__ __align__(16) char ldsc[];

  // ---- XCD-aware supertile swizzle (bijective over the 32x32 grid) ----
  const int bid = blockIdx.x;
  const int chunk = bid & 7;          // XCD id (round-robin dispatch)
  const int slot = bid >> 3;          // 0..127: per-XCD issue order
  const int by = chunk * 4 + ((slot >> 2) & 3);
  const int bx = (slot >> 4) * 4 + (slot & 3);
  const int brow = by * BM;
  const int bcol = bx * BN;

  const int tid = threadIdx.x;
  const int w = tid >> 6;             // wave 0..7
  const int lane = tid & 63;
  const int wr = w >> 2;              // 0..1: rows [wr*128, +128)
  const int wc = w & 3;               // 0..3: cols [wc*64, +64)

  f32x4 acc[8][4];
#pragma unroll
  for (int m = 0; m < 8; ++m)
#pragma unroll
    for (int n = 0; n < 4; ++n) acc[m][n] = (f32x4)0.0f;

  // ---- staging: 1 gload16 per half per wave (16 rows x 64B) ----
  const int srow = lane >> 2;                       // 0..15
  const int spair = (lane & 3) ^ ((lane >> 3) & 3); // swizzled source 16B-pair

  auto STAGE_TILE = [&](int st) {
    const int stm = st & (KT - 1);     // wrap: dead prefetch on last phases
    const int bo = (st & 3) * BUF_BYTES;
#pragma unroll
    for (int h = 0; h < 4; ++h) {
      const unsigned char* gbase =
          (h < 2) ? An + (size_t)brow * DDIM : Bn + (size_t)bcol * DDIM;
      const int rowt = (h & 1) * 128 + w * 16;
      const unsigned char* g =
          gbase + (size_t)(rowt + srow) * DDIM + stm * BK + spair * 16;
      char* dst = ldsc + bo + ((h >= 2) ? TILE_BYTES : 0) + rowt * 64;
      gload16(g, dst);
    }
  };

  const int hi = lane >> 4;                 // 0..3 (k-group)
  const int l15 = lane & 15;
  const int e8 = ((l15 >> 1) & 3) << 1;     // even XOR on 8B-slot index

  // per-lane byte offsets (constant across phases); reads then use
  // compile-time immediate offsets -> ~zero VALU per ds_read
  const int paoff = (wr * 128 + l15) * 64;                  // A row base
  const int pboff = TILE_BYTES + (wc * 64 + l15) * 64;      // B row base
  const int sa0 = ((0 + hi) ^ e8) * 8;                      // slot kk=0
  const int sa1 = ((4 + hi) ^ e8) * 8;                      // slot kk=1

  long long afr[16], bfr[8];

  auto READF = [&](int bufb) {
    const char* pa0 = ldsc + bufb * BUF_BYTES + paoff + sa0;
    const char* pa1 = ldsc + bufb * BUF_BYTES + paoff + sa1;
    const char* pb0 = ldsc + bufb * BUF_BYTES + pboff + sa0;
    const char* pb1 = ldsc + bufb * BUF_BYTES + pboff + sa1;
#pragma unroll
    for (int qm = 0; qm < 2; ++qm)
#pragma unroll
      for (int mi = 0; mi < 4; ++mi) {
        afr[qm * 8 + mi * 2 + 0] =
            *(const long long*)(pa0 + (qm * 64 + mi * 16) * 64);
        afr[qm * 8 + mi * 2 + 1] =
            *(const long long*)(pa1 + (qm * 64 + mi * 16) * 64);
      }
#pragma unroll
    for (int qn = 0; qn < 2; ++qn)
#pragma unroll
      for (int ni = 0; ni < 2; ++ni) {
        bfr[qn * 4 + ni * 2 + 0] =
            *(const long long*)(pb0 + (qn * 32 + ni * 16) * 64);
        bfr[qn * 4 + ni * 2 + 1] =
            *(const long long*)(pb1 + (qn * 32 + ni * 16) * 64);
      }
  };

  // ---- prologue: tiles 0,1 staged; T0 confirmed ----
  STAGE_TILE(0);
  STAGE_TILE(1);
  VMC(4);
  SBAR();

  // ---- main loop: 1 phase per K-tile, 1 barrier per phase ----
  // Safety: stage targets buf((t+2)&3) whose last readers ran at ph(t-2),
  // >=2 barriers back; each wave's reads are consumed by its own MFMAs
  // before it passes the next barrier.
#pragma unroll
  for (int t = 0; t < KT; ++t) {
    READF(t & 3);            // 24 x ds_read_b64 (whole K-tile)
    STAGE_TILE(t + 2);       // 4 x gload16 -> buf((t+2)&3)
    VMC(4);                  // T(t+1) landed (T(t+2)'s 4 still in flight)
    SBAR();
    __builtin_amdgcn_s_setprio(1);
#pragma unroll
    for (int kk = 0; kk < 2; ++kk)       // kk-major: 32 indep chains
#pragma unroll
      for (int qm = 0; qm < 2; ++qm)
#pragma unroll
        for (int mi = 0; mi < 4; ++mi)
#pragma unroll
          for (int qn = 0; qn < 2; ++qn)
#pragma unroll
            for (int ni = 0; ni < 2; ++ni)
              acc[qm * 4 + mi][qn * 2 + ni] =
                  __builtin_amdgcn_mfma_f32_16x16x32_fp8_fp8(
                      afr[qm * 8 + mi * 2 + kk], bfr[qn * 4 + ni * 2 + kk],
                      acc[qm * 4 + mi][qn * 2 + ni], 0, 0, 0);
    __builtin_amdgcn_s_setprio(0);
  }
  VMC(0);   // retire dead wrap-prefetches

  // ---- epilogue: acc = 400*cos; exp2(acc/20*L2E - 20*L2E); col reduce ----
  // C/D layout: col = lane&15, row = (lane>>4)*4 + reg  [m89/m91]
  const float L2E20 = 1.4426950408889634f / 20.0f;
  const float NEG = -SHIFT * 1.4426950408889634f;
#pragma unroll
  for (int m = 0; m < 8; ++m) {
#pragma unroll
    for (int r = 0; r < 4; ++r) {
      float s = 0.0f;
#pragma unroll
      for (int n = 0; n < 4; ++n)
        s += exp2f(fmaf(acc[m][n][r], L2E20, NEG));
      s += __shfl_xor(s, 1);
      s += __shfl_xor(s, 2);
      s += __shfl_xor(s, 4);
      s += __shfl_xor(s, 8);
      if (l15 == 0)
        atomicAdd(&rowsum[brow + wr * 128 + m * 16 + hi * 4 + r], s);
    }
  }
}

// -------------------------------------------------------------------------
// Kernel 3: out = -( mean_i( log(rowsum_i) + 20 ) )
// -------------------------------------------------------------------------
__global__ __launch_bounds__(1024) void finalize_lse(
    const float* __restrict__ rowsum, float* __restrict__ out) {
  __shared__ float sm[16];
  float s = 0.0f;
  for (int i = threadIdx.x; i < NROW; i += 1024) s += logf(rowsum[i]);
#pragma unroll
  for (int off = 32; off; off >>= 1) s += __shfl_xor(s, off);
  int w = threadIdx.x >> 6;
  if ((threadIdx.x & 63) == 0) sm[w] = s;
  __syncthreads();
  if (threadIdx.x == 0) {
    float t = 0.0f;
#pragma unroll
    for (int i = 0; i < 16; ++i) t += sm[i];
    out[0] = -(t / (float)NROW + SHIFT);
  }
}

// -------------------------------------------------------------------------
extern "C" void kernel_launch(void* const* d_in, const int* in_sizes, int n_in,
                              void* d_out, int out_size, void* d_ws,
                              size_t ws_size, hipStream_t stream) {
  const float* z1 = (const float*)d_in[0];
  const float* z2 = (const float*)d_in[1];
  float* out = (float*)d_out;

  char* ws = (char*)d_ws;
  unsigned char* z1n = (unsigned char*)ws;                              // 4 MB
  unsigned char* z2n = (unsigned char*)(ws + (size_t)NROW * DDIM);      // 4 MB
  float* rowsum = (float*)(ws + (size_t)2 * NROW * DDIM);               // 32 KB

  static bool attr_set = false;
  if (!attr_set) {
    hipFuncSetAttribute((const void*)gemm_lse,
                        hipFuncAttributeMaxDynamicSharedMemorySize, LDS_BYTES);
    attr_set = true;
  }

  normalize_rows<<<dim3((2 * NROW) / 4), dim3(256), 0, stream>>>(z1, z2, z1n,
                                                                 z2n, rowsum);
  gemm_lse<<<dim3((NROW / BM) * (NROW / BN)), dim3(512), LDS_BYTES, stream>>>(
      z1n, z2n, rowsum);
  finalize_lse<<<dim3(1), dim3(1024), 0, stream>>>(rowsum, out);
}